// Round 1
// baseline (43.174 us; speedup 1.0000x reference)
//
#include <hip/hip_runtime.h>
#include <math.h>

// SMorphLayer: B=8, C=1, H=W=128, F=16, KH=KW=5, stride 1, VALID -> OH=OW=124
// y[b,f,oy,ox] = sm(p + k1[f]) + sm(-p + k2[f]) + bias[f]
// sm(t) = sum(t*e^t)/sum(e^t)  (alpha=1; max-shift cancels exactly)
// Factorization: e^{p_j + k1_fj} = E_j * e1_fj with E_j = e^{p_j}.
//   num1 = sum_j p_j*E_j*e1_fj + E_j*(k1_fj*e1_fj);  den1 = sum_j E_j*e1_fj
//   num2 = sum_j I_j*(k2_fj*e2_fj) - p_j*I_j*e2_fj;  den2 = sum_j I_j*e2_fj
// Filter constants (e1, k1*e1, e2, k2*e2) precomputed into d_ws (6.4 KB),
// read in the main kernel at wave-uniform addresses -> scalar loads.

#define Bn 8
#define Fn 16
#define Hn 128
#define Wn 128
#define KHn 5
#define KWn 5
#define OHn 124
#define OWn 124
#define TILE 16

__global__ __launch_bounds__(512) void smorph_precompute(
    const float* __restrict__ k1, const float* __restrict__ k2,
    float* __restrict__ cc /* [25][16] float4 = {e1, k1*e1, e2, k2*e2} */) {
  int i = blockIdx.x * blockDim.x + threadIdx.x;
  if (i < Fn * 25) {
    int f = i / 25, j = i % 25;
    float a = k1[i], b = k2[i];
    float e1 = __expf(a), e2 = __expf(b);
    ((float4*)cc)[j * Fn + f] = make_float4(e1, a * e1, e2, b * e2);
  }
}

__global__ __launch_bounds__(256) void smorph_main(
    const float* __restrict__ x, const float* __restrict__ cc,
    const float* __restrict__ bias, float* __restrict__ out) {
  __shared__ float tile[TILE + KHn - 1][TILE + KWn - 1];  // 20x20

  const int b = blockIdx.z;
  const int ox0 = blockIdx.x * TILE, oy0 = blockIdx.y * TILE;
  const int tid = threadIdx.x;
  const float* xb = x + b * Hn * Wn;

  // stage 20x20 input tile (guarded at image edge)
  for (int i = tid; i < (TILE + 4) * (TILE + 4); i += 256) {
    int r = i / (TILE + 4), c = i % (TILE + 4);
    int gy = oy0 + r, gx = ox0 + c;
    tile[r][c] = (gy < Hn && gx < Wn) ? xb[gy * Wn + gx] : 0.0f;
  }
  __syncthreads();

  const int lx = tid & (TILE - 1), ly = tid >> 4;
  const int ox = ox0 + lx, oy = oy0 + ly;
  if (ox >= OWn || oy >= OHn) return;

  float num1[Fn], den1[Fn], num2[Fn], den2[Fn];
#pragma unroll
  for (int f = 0; f < Fn; ++f) {
    num1[f] = 0.f; den1[f] = 0.f; num2[f] = 0.f; den2[f] = 0.f;
  }

#pragma unroll
  for (int kh = 0; kh < KHn; ++kh) {
#pragma unroll
    for (int kw = 0; kw < KWn; ++kw) {
      const float p = tile[ly + kh][lx + kw];
      const float E = __expf(p);
      const float I = __expf(-p);
      const float A1 = p * E;
      const float A2 = p * I;
      const float4* c4 = ((const float4*)cc) + (kh * KWn + kw) * Fn;
#pragma unroll
      for (int f = 0; f < Fn; ++f) {
        const float4 v = c4[f];  // uniform -> s_load
        num1[f] += A1 * v.x + E * v.y;
        den1[f] += E * v.x;
        num2[f] += I * v.w - A2 * v.z;
        den2[f] += I * v.z;
      }
    }
  }

  const int base = (b * Fn * OHn + oy) * OWn + ox;
#pragma unroll
  for (int f = 0; f < Fn; ++f) {
    out[base + f * OHn * OWn] =
        __fdividef(num1[f], den1[f]) + __fdividef(num2[f], den2[f]) + bias[f];
  }
}

extern "C" void kernel_launch(void* const* d_in, const int* in_sizes, int n_in,
                              void* d_out, int out_size, void* d_ws, size_t ws_size,
                              hipStream_t stream) {
  const float* x    = (const float*)d_in[0];
  const float* k1   = (const float*)d_in[1];
  const float* k2   = (const float*)d_in[2];
  const float* bias = (const float*)d_in[3];
  float* out = (float*)d_out;
  float* cc  = (float*)d_ws;  // 25*16*4 floats = 6400 B

  smorph_precompute<<<1, 512, 0, stream>>>(k1, k2, cc);
  dim3 grid((OWn + TILE - 1) / TILE, (OHn + TILE - 1) / TILE, Bn);
  smorph_main<<<grid, 256, 0, stream>>>(x, cc, bias, out);
}

// Round 2
// 36.274 us; speedup vs baseline: 1.1902x; 1.1902x over previous
//
#include <hip/hip_runtime.h>
#include <math.h>

// SMorphLayer: B=8, C=1, H=W=128, F=16, KH=KW=5, stride 1 -> OH=OW=124
// y[b,f,oy,ox] = sm(p + k1[f]) + sm(-p + k2[f]) + bias[f],
// sm(t) = sum(t e^t)/sum(e^t) (alpha=1, max-shift cancels exactly).
// Factorization: e^{p_j + k1_fj} = E_j * e1_fj, E_j = e^{p_j}, I_j = e^{-p_j}.
//   n1 = sum_j fma(p_j, e1, k1*e1) * E_j     d1 = sum_j E_j * e1
//   n2 = sum_j fma(-p_j, e2, k2*e2) * I_j    d2 = sum_j I_j * e2
//
// Round-1 restructure: filter loop OUTERMOST (4 live accumulators instead of
// 64), per-thread p/E/I arrays computed once (75 VGPRs, static indices only),
// constants at wave-uniform addresses with a 4-float working set per step.
// Filters split across 2 blocks for 4 waves/SIMD.

#define Bn 8
#define Fn 16
#define Hn 128
#define Wn 128
#define OHn 124
#define OWn 124
#define TILE 16
#define FSPLIT 2
#define FPB (Fn / FSPLIT)  // 8 filters per block

__global__ __launch_bounds__(256) void smorph_precompute(
    const float* __restrict__ k1, const float* __restrict__ k2,
    float4* __restrict__ cc /* [F][25] = {e1, k1*e1, e2, k2*e2} */) {
  int i = blockIdx.x * blockDim.x + threadIdx.x;
  if (i < Fn * 25) {
    float a = k1[i], b = k2[i];
    float e1 = __expf(a), e2 = __expf(b);
    cc[i] = make_float4(e1, a * e1, e2, b * e2);
  }
}

__global__ __launch_bounds__(256) void smorph_main(
    const float* __restrict__ x, const float4* __restrict__ cc,
    const float* __restrict__ bias, float* __restrict__ out) {
  __shared__ float tile[TILE + 4][TILE + 4];  // 20x20 input tile

  const int z = blockIdx.z;
  const int b = z >> 1, fh = z & 1;
  const int ox0 = blockIdx.x * TILE, oy0 = blockIdx.y * TILE;
  const int tid = threadIdx.x;
  const float* xb = x + b * (Hn * Wn);

  for (int i = tid; i < (TILE + 4) * (TILE + 4); i += 256) {
    int r = i / (TILE + 4), c = i % (TILE + 4);
    int gy = oy0 + r, gx = ox0 + c;
    tile[r][c] = (gy < Hn && gx < Wn) ? xb[gy * Wn + gx] : 0.0f;
  }
  __syncthreads();

  const int lx = tid & 15, ly = tid >> 4;
  const int ox = ox0 + lx, oy = oy0 + ly;
  if (ox >= OWn || oy >= OHn) return;

  // Per-thread patch state, computed once, statically indexed.
  float pv[25], Ev[25], Iv[25];
#pragma unroll
  for (int kh = 0; kh < 5; ++kh)
#pragma unroll
    for (int kw = 0; kw < 5; ++kw) {
      const int j = kh * 5 + kw;
      const float p = tile[ly + kh][lx + kw];
      pv[j] = p;
      Ev[j] = __expf(p);
      Iv[j] = __expf(-p);
    }

  const int obase = ((b * Fn + fh * FPB) * OHn + oy) * OWn + ox;
#pragma unroll 1
  for (int fi = 0; fi < FPB; ++fi) {
    const int f = fh * FPB + fi;
    const float4* __restrict__ c4 = cc + f * 25;  // wave-uniform
    float n1 = 0.f, d1 = 0.f, n2 = 0.f, d2 = 0.f;
#pragma unroll
    for (int j = 0; j < 25; ++j) {
      const float4 v = c4[j];
      const float t1 = fmaf(pv[j], v.x, v.y);   // p*e1 + k1e1
      n1 = fmaf(t1, Ev[j], n1);
      d1 = fmaf(Ev[j], v.x, d1);
      const float t2 = fmaf(-pv[j], v.z, v.w);  // -p*e2 + k2e2
      n2 = fmaf(t2, Iv[j], n2);
      d2 = fmaf(Iv[j], v.z, d2);
    }
    out[obase + fi * (OHn * OWn)] =
        __fdividef(n1, d1) + __fdividef(n2, d2) + bias[f];
  }
}

extern "C" void kernel_launch(void* const* d_in, const int* in_sizes, int n_in,
                              void* d_out, int out_size, void* d_ws, size_t ws_size,
                              hipStream_t stream) {
  const float* x    = (const float*)d_in[0];
  const float* k1   = (const float*)d_in[1];
  const float* k2   = (const float*)d_in[2];
  const float* bias = (const float*)d_in[3];
  float* out = (float*)d_out;
  float4* cc = (float4*)d_ws;  // 16*25*16 B = 6400 B

  smorph_precompute<<<2, 256, 0, stream>>>(k1, k2, cc);
  dim3 grid((OWn + TILE - 1) / TILE, (OHn + TILE - 1) / TILE, Bn * FSPLIT);
  smorph_main<<<grid, 256, 0, stream>>>(x, cc, bias, out);
}

// Round 3
// 17.896 us; speedup vs baseline: 2.4126x; 2.0270x over previous
//
#include <hip/hip_runtime.h>
#include <math.h>

// SMorphLayer: B=8, C=1, H=W=128, F=16, KH=KW=5, stride 1 -> OH=OW=124
// y[b,f,oy,ox] = sm(p + k1[f]) + sm(-p + k2[f]) + bias[f],
// sm(t) = sum(t e^t)/sum(e^t) (alpha=1, max-shift cancels exactly).
// Factorization: e^{p_j+k1_fj} = E_j*e1_fj, E_j=e^{p_j}, I_j=e^{-p_j}:
//   n1 = sum_j fma(p, e1, k1e1)*E   d1 = sum_j E*e1
//   n2 = sum_j fma(-p, e2, k2e2)*I  d2 = sum_j I*e2
//
// Round-2 restructure (register-pressure-driven):
//  * SINGLE fused kernel; per-block constant table (e1,k1e1,e2,k2e2) built in
//    LDS (400 exps/block, noise) -> no second launch, no global round-trip.
//  * j-OUTER / f-inner(8): live set = 32 acc + 8 in-flight float4 + {p,E,I}
//    ~= 90 VGPR, no per-thread arrays, no runtime indexing (rule #20 safe).
//  * Constants read as wave-uniform ds_read_b128 broadcasts (no conflicts),
//    reuse distance ~6 FMAs.

#define Bn 8
#define Fn 16
#define Hn 128
#define Wn 128
#define OHn 124
#define OWn 124
#define TILE 16
#define FSPLIT 2
#define FPB (Fn / FSPLIT)  // 8 filters per block

__global__ __launch_bounds__(256) void smorph_fused(
    const float* __restrict__ x, const float* __restrict__ k1,
    const float* __restrict__ k2, const float* __restrict__ bias,
    float* __restrict__ out) {
  __shared__ float4 ccs[Fn * 25];            // 6400 B: {e1, k1*e1, e2, k2*e2}
  __shared__ float bs[Fn];                   // 64 B
  __shared__ float tile[TILE + 4][TILE + 4]; // 20x20 input tile, 1600 B

  const int z = blockIdx.z;
  const int b = z >> 1, fh = z & 1;
  const int ox0 = blockIdx.x * TILE, oy0 = blockIdx.y * TILE;
  const int tid = threadIdx.x;
  const float* xb = x + b * (Hn * Wn);

  // Stage input tile (guarded at image edge).
  for (int i = tid; i < (TILE + 4) * (TILE + 4); i += 256) {
    int r = i / (TILE + 4), c = i % (TILE + 4);
    int gy = oy0 + r, gx = ox0 + c;
    tile[r][c] = (gy < Hn && gx < Wn) ? xb[gy * Wn + gx] : 0.0f;
  }
  // Build constant table in LDS (all 16 filters; 2 exps per entry).
  for (int i = tid; i < Fn * 25; i += 256) {
    float a = k1[i], c = k2[i];
    float e1 = __expf(a), e2 = __expf(c);
    ccs[i] = make_float4(e1, a * e1, e2, c * e2);
  }
  if (tid < Fn) bs[tid] = bias[tid];
  __syncthreads();

  const int lx = tid & 15, ly = tid >> 4;
  const int ox = ox0 + lx, oy = oy0 + ly;
  if (ox >= OWn || oy >= OHn) return;

  float n1[FPB], d1[FPB], n2[FPB], d2[FPB];
#pragma unroll
  for (int fi = 0; fi < FPB; ++fi) {
    n1[fi] = 0.f; d1[fi] = 0.f; n2[fi] = 0.f; d2[fi] = 0.f;
  }

#pragma unroll
  for (int kh = 0; kh < 5; ++kh) {
#pragma unroll
    for (int kw = 0; kw < 5; ++kw) {
      const int j = kh * 5 + kw;
      const float p = tile[ly + kh][lx + kw];
      const float E = __expf(p);
      const float I = __expf(-p);
      const float4* __restrict__ cj = ccs + fh * (FPB * 25) + j;
#pragma unroll
      for (int fi = 0; fi < FPB; ++fi) {
        const float4 v = cj[fi * 25];  // uniform broadcast ds_read_b128
        const float t1 = fmaf(p, v.x, v.y);
        n1[fi] = fmaf(t1, E, n1[fi]);
        d1[fi] = fmaf(E, v.x, d1[fi]);
        const float t2 = fmaf(-p, v.z, v.w);
        n2[fi] = fmaf(t2, I, n2[fi]);
        d2[fi] = fmaf(I, v.z, d2[fi]);
      }
    }
  }

  const int obase = ((b * Fn + fh * FPB) * OHn + oy) * OWn + ox;
#pragma unroll
  for (int fi = 0; fi < FPB; ++fi) {
    out[obase + fi * (OHn * OWn)] = __fdividef(n1[fi], d1[fi]) +
                                    __fdividef(n2[fi], d2[fi]) +
                                    bs[fh * FPB + fi];
  }
}

extern "C" void kernel_launch(void* const* d_in, const int* in_sizes, int n_in,
                              void* d_out, int out_size, void* d_ws, size_t ws_size,
                              hipStream_t stream) {
  const float* x    = (const float*)d_in[0];
  const float* k1   = (const float*)d_in[1];
  const float* k2   = (const float*)d_in[2];
  const float* bias = (const float*)d_in[3];
  float* out = (float*)d_out;

  dim3 grid((OWn + TILE - 1) / TILE, (OHn + TILE - 1) / TILE, Bn * FSPLIT);
  smorph_fused<<<grid, 256, 0, stream>>>(x, k1, k2, bias, out);
}